// Round 16
// baseline (209.628 us; speedup 1.0000x reference)
//
#include <hip/hip_runtime.h>
#include <hip/hip_bf16.h>

#define C_ 256
#define S_ 1024
#define NH_ 8
#define DH_ 32
#define NSIDE 16
#define MTOT (NSIDE * S_) // 16384

typedef __hip_bfloat16 bf16;
typedef short bf8_t __attribute__((ext_vector_type(8)));  // 8 bf16 = 4 VGPRs
typedef float f4_t __attribute__((ext_vector_type(4)));   // 4 fp32 acc

// exp path: prefer raw v_exp_f32 (exp2) with log2e folded into the Q scale
#if __has_builtin(__builtin_amdgcn_exp2f)
#define QSCALE 0.25504167f  // 1/sqrt(32) * log2(e)
__device__ __forceinline__ float fastexp(float x) { return __builtin_amdgcn_exp2f(x); }
#else
#define QSCALE 0.17677669529663689f  // 1/sqrt(32)
__device__ __forceinline__ float fastexp(float x) { return __expf(x); }
#endif

__device__ __forceinline__ float b2f(bf16 x) { return __bfloat162float(x); }
__device__ __forceinline__ bf16 f2b(float x) { return __float2bfloat16(x); }
__device__ __forceinline__ unsigned short f2bu(float x) {
    bf16 h = f2b(x);
    return *reinterpret_cast<unsigned short*>(&h);
}
// truncating pack of two floats to bf16x2 via one v_perm_b32
__device__ __forceinline__ unsigned pack_trunc(float a, float b) {
    return __builtin_amdgcn_perm(__float_as_uint(b), __float_as_uint(a), 0x07060302u);
}

__device__ __forceinline__ float block_sum(float v, float* red) {
#pragma unroll
    for (int off = 1; off < 64; off <<= 1) v += __shfl_xor(v, off);
    __syncthreads();
    if ((threadIdx.x & 63) == 0) red[threadIdx.x >> 6] = v;
    __syncthreads();
    float r = red[0] + red[1] + red[2] + red[3];
    __syncthreads();
    return r;
}

// Fragment-major packing: element (n,k) of an [N][K] matrix ->
// block (n>>4, k>>5) of 512 elems; within block: [(k>>3)&3][n&15][k&7]
__device__ __forceinline__ void packone(const float* __restrict__ src, bf16* __restrict__ dst,
                                        int i, int kshift) {
    int n = i >> kshift, k = i & ((1 << kshift) - 1);
    size_t a = ((size_t)((n >> 4) * (1 << (kshift - 5)) + (k >> 5)) << 9) +
               (((k >> 3) & 3) << 7) + ((n & 15) << 3) + (k & 7);
    dst[a] = f2b(src[i]);
}

// ---- prep: blocks 0..255 = LN of pair tokens (+ mean partials); 256+ = weight packing ----
__global__ __launch_bounds__(256) void prep_kernel(
    const float* __restrict__ src, const int* __restrict__ pair,
    const float* __restrict__ w, const float* __restrict__ b,
    bf16* __restrict__ dst, float* __restrict__ partial,
    const float* __restrict__ wa, bf16* __restrict__ oa,
    const float* __restrict__ wb_, bf16* __restrict__ ob,
    const float* __restrict__ wc, bf16* __restrict__ oc,
    const float* __restrict__ wd, bf16* __restrict__ od) {
    int bid = blockIdx.x;
    if (bid >= 256) {
        int i = (bid - 256) * 256 + threadIdx.x;
        if (i < 196608) { packone(wa, oa, i, 8); return; }       // in_proj_w 768x256
        i -= 196608;
        if (i < 65536) { packone(wb_, ob, i, 8); return; }       // out_proj_w 256x256
        i -= 65536;
        if (i < 262144) { packone(wc, oc, i, 8); return; }       // mlp_w1 1024x256
        i -= 262144;
        if (i < 262144) packone(wd, od, i, 10);                  // mlp_w2 256x1024
        return;
    }
    __shared__ float psum[4][64], psq[4][64], mean_s[64], rstd_s[64];
    __shared__ float wb[512];
    __shared__ __align__(16) short Ys[64][264];
    int sb = bid & 15, u = bid >> 4;
    int bi = pair[u];
    int tid = threadIdx.x;
    wb[tid] = w[tid];
    wb[256 + tid] = b[tid];
    int sl = tid & 63, cp = tid >> 6;
    int s = sb * 64 + sl;
    const float* zb = src + (size_t)bi * C_ * S_ + s;
    float sum = 0.f, sq = 0.f;
    for (int c = cp * 64; c < cp * 64 + 64; ++c) {
        float x = zb[(size_t)c * S_];
        sum += x;
        sq += x * x;
    }
    psum[cp][sl] = sum;
    psq[cp][sl] = sq;
    __syncthreads();
    if (tid < 64) {
        float sm = psum[0][tid] + psum[1][tid] + psum[2][tid] + psum[3][tid];
        float q2 = psq[0][tid] + psq[1][tid] + psq[2][tid] + psq[3][tid];
        float mean = sm * (1.0f / C_);
        float var = q2 * (1.0f / C_) - mean * mean;
        mean_s[tid] = mean;
        rstd_s[tid] = rsqrtf(var + 1e-5f);
    }
    __syncthreads();
    float mean = mean_s[sl], rstd = rstd_s[sl];
    int m = u * S_ + s;
    size_t tile8 = (size_t)(m >> 4) * 8;
    for (int c8 = 0; c8 < 64; c8 += 8) {
        int c = cp * 64 + c8;
        bf8_t pk;
#pragma unroll
        for (int j = 0; j < 8; ++j) {
            float x = zb[(size_t)(c + j) * S_];
            float y = (x - mean) * rstd * wb[c + j] + wb[256 + c + j];
            pk[j] = (short)f2bu(y);
        }
        *reinterpret_cast<bf8_t*>(&Ys[sl][c]) = pk;
        *reinterpret_cast<bf8_t*>(dst + ((tile8 + (c >> 5)) << 9) +
                                  (((c >> 3) & 3) << 7) + ((m & 15) << 3)) = pk;
    }
    __syncthreads();
    float csum = 0.f;
#pragma unroll 8
    for (int t = 0; t < 64; ++t)
        csum += b2f(*reinterpret_cast<const bf16*>(&Ys[t][tid]));
    partial[((size_t)u * 16 + sb) * C_ + tid] = csum;
}

// ---- QKV projection GEMM (blocks 0..767) + gate (block 768) ----
// qpk/kpk: [u][h][tok][d]   vpk: [u][h][kt][d][key32]
__global__ __launch_bounds__(256) void gemm_qkv(
    const bf16* __restrict__ Apk, const bf16* __restrict__ Wpk, const float* __restrict__ bias,
    bf16* __restrict__ qpk, bf16* __restrict__ kpk, bf16* __restrict__ vpk,
    const float* __restrict__ partial, const float* __restrict__ gate_scale,
    float* __restrict__ gatef, float* __restrict__ out_gate, float* __restrict__ out_sim) {
    __shared__ float red[4];
    int tid = threadIdx.x;
    if (blockIdx.x == 768) {
        int c = tid;
        for (int p = 0; p < 8; ++p) {
            float mi = 0.f, mj = 0.f;
            for (int sy = 0; sy < 16; ++sy) {
                mi += partial[((size_t)(2 * p) * 16 + sy) * C_ + c];
                mj += partial[((size_t)(2 * p + 1) * 16 + sy) * C_ + c];
            }
            mi *= (1.f / S_);
            mj *= (1.f / S_);
            float ii = block_sum(mi * mi, red);
            float jj = block_sum(mj * mj, red);
            float ij = block_sum(mi * mj, red);
            if (c == 0) {
                float ni = fmaxf(sqrtf(ii), 1e-6f);
                float nj = fmaxf(sqrtf(jj), 1e-6f);
                float sim = ij / (ni * nj);
                float gate = 1.f / (1.f + expf(-gate_scale[0] * sim));
                gatef[p] = gate;
                out_gate[p] = gate;
                out_sim[p] = sim;
            }
        }
        return;
    }
    int wv = tid >> 6, lane = tid & 63;
    int ln15 = lane & 15, quad = lane >> 4;
    int idx = blockIdx.x * 4 + wv;
    int mt = idx / 12, nt = idx % 12;
    int m0 = mt * 64, n0 = nt * 64;

    f4_t acc[4][4];
#pragma unroll
    for (int i = 0; i < 4; ++i)
#pragma unroll
        for (int j = 0; j < 4; ++j) acc[i][j] = (f4_t)(0.0f);

    const bf16* Ab = Apk + ((size_t)mt << 14) + lane * 8;
    const bf16* Wb = Wpk + ((size_t)nt << 14) + lane * 8;

    bf8_t a0[4], w0[4], a1[4], w1[4];
#pragma unroll
    for (int i = 0; i < 4; ++i) {
        a0[i] = *reinterpret_cast<const bf8_t*>(Ab + ((size_t)(i * 8) << 9));
        w0[i] = *reinterpret_cast<const bf8_t*>(Wb + ((size_t)(i * 8) << 9));
    }
    for (int kch = 0; kch < 8; kch += 2) {
#pragma unroll
        for (int i = 0; i < 4; ++i) {
            a1[i] = *reinterpret_cast<const bf8_t*>(Ab + ((size_t)(i * 8 + kch + 1) << 9));
            w1[i] = *reinterpret_cast<const bf8_t*>(Wb + ((size_t)(i * 8 + kch + 1) << 9));
        }
#pragma unroll
        for (int i = 0; i < 4; ++i)
#pragma unroll
            for (int j = 0; j < 4; ++j)
                acc[i][j] = __builtin_amdgcn_mfma_f32_16x16x32_bf16(a0[i], w0[j], acc[i][j], 0, 0, 0);
        if (kch + 2 < 8) {
#pragma unroll
            for (int i = 0; i < 4; ++i) {
                a0[i] = *reinterpret_cast<const bf8_t*>(Ab + ((size_t)(i * 8 + kch + 2) << 9));
                w0[i] = *reinterpret_cast<const bf8_t*>(Wb + ((size_t)(i * 8 + kch + 2) << 9));
            }
        }
#pragma unroll
        for (int i = 0; i < 4; ++i)
#pragma unroll
            for (int j = 0; j < 4; ++j)
                acc[i][j] = __builtin_amdgcn_mfma_f32_16x16x32_bf16(a1[i], w1[j], acc[i][j], 0, 0, 0);
    }

#pragma unroll
    for (int i = 0; i < 4; ++i) {
#pragma unroll
        for (int j = 0; j < 4; ++j) {
            int coln = n0 + j * 16 + ln15;
            float bs = bias[coln];
            int row0 = m0 + i * 16 + quad * 4;   // r=0 row; u and kt uniform over r
            int u = row0 >> 10, s0v = row0 & 1023;
            if (coln < 256) {
                int h = coln >> 5, d = coln & 31;
                bf16* qp = qpk + (((size_t)u * 8 + h) * 1024 + s0v) * 32 + d;
#pragma unroll
                for (int r = 0; r < 4; ++r)
                    qp[r * 32] = f2b((acc[i][j][r] + bs) * QSCALE);
            } else if (coln < 512) {
                int c = coln - 256, h = c >> 5, d = c & 31;
                bf16* kp = kpk + (((size_t)u * 8 + h) * 1024 + s0v) * 32 + d;
#pragma unroll
                for (int r = 0; r < 4; ++r)
                    kp[r * 32] = f2b(acc[i][j][r] + bs);
            } else {
                int c = coln - 512, h = c >> 5, d = c & 31;
                ushort4 pk;  // 4 consecutive keys (r maps to s) -> one 8B store
#pragma unroll
                for (int r = 0; r < 4; ++r)
                    ((unsigned short*)&pk)[r] = f2bu(acc[i][j][r] + bs);
                *reinterpret_cast<ushort4*>(
                    vpk + ((((size_t)u * 8 + h) * 32 + (s0v >> 5)) * 32 + d) * 32 + (s0v & 31)) = pk;
            }
        }
    }
}

// ---- attention v8: 64 q/wave (4 qt), block = 256 q of one (u,h); waves share K/V in L1 ----
__global__ __launch_bounds__(256, 2) void attn_mfma(const bf16* __restrict__ qpk,
                                                    const bf16* __restrict__ kpk,
                                                    const bf16* __restrict__ vpk,
                                                    bf16* __restrict__ ctx) {
    __shared__ __align__(16) short smem[4 * 4608]; // per wave: 4 qt x 16 q x 72
    int tid = threadIdx.x;
    int wv = tid >> 6, lane = tid & 63;
    int ln15 = lane & 15, quad = lane >> 4;
    int bid = blockIdx.x;
    int g = bid >> 5, rem = bid & 31;
    int qb = rem >> 3, xcd = rem & 7;
    int uh = g * 8 + xcd;
    int u = uh >> 3, h = uh & 7, up = u ^ 1;
    int q0 = qb * 256 + wv * 64;
    short* PL = smem + wv * 4608;

    const bf16* Qb = qpk + (size_t)uh * 32768;
    const bf16* Kb = kpk + ((size_t)(up * 8 + h)) * 32768;
    const bf16* Vb = vpk + ((size_t)(up * 8 + h)) * 32768;

    bf8_t qf[4];
#pragma unroll
    for (int qt = 0; qt < 4; ++qt)
        qf[qt] = *reinterpret_cast<const bf8_t*>(Qb + (size_t)(q0 + qt * 16 + ln15) * 32 + quad * 8);

    bf8_t ones;
#pragma unroll
    for (int t = 0; t < 8; ++t) ones[t] = (short)0x3F80;

    const bf16* kp = Kb + ln15 * 32 + quad * 8;
    const bf16* vp = Vb + ln15 * 32 + quad * 8;
    short* plw = PL + ln15 * 72 + quad * 4;
    const short* plr = PL + ln15 * 72 + quad * 8;

    f4_t o[2][4];  // [dh][qt]
#pragma unroll
    for (int i = 0; i < 2; ++i)
#pragma unroll
        for (int j = 0; j < 4; ++j) o[i][j] = (f4_t)(0.0f);
    f4_t lacc[4];
#pragma unroll
    for (int j = 0; j < 4; ++j) lacc[j] = (f4_t)(0.0f);
    f4_t zf = (f4_t)(0.0f);

    bf8_t kfA[4], vtA[2][2], kfB[4], vtB[2][2];
#pragma unroll
    for (int t = 0; t < 4; ++t)
        kfA[t] = *reinterpret_cast<const bf8_t*>(kp + (size_t)(t * 16) * 32);
#pragma unroll
    for (int kc = 0; kc < 2; ++kc)
#pragma unroll
        for (int dh = 0; dh < 2; ++dh)
            vtA[kc][dh] = *reinterpret_cast<const bf8_t*>(vp + (size_t)kc * 1024 + dh * 512);

    auto step = [&](bf8_t (&kfC)[4], bf8_t (&vtC)[2][2],
                    bf8_t (&kfN)[4], bf8_t (&vtN)[2][2], int itn) {
        {
            f4_t st[4];
#pragma unroll
            for (int kh = 0; kh < 4; ++kh)
                st[kh] = __builtin_amdgcn_mfma_f32_16x16x32_bf16(kfC[kh], qf[0], zf, 0, 0, 0);
            if (itn < 16) {
                int k0n = itn * 64;
#pragma unroll
                for (int t = 0; t < 4; ++t)
                    kfN[t] = *reinterpret_cast<const bf8_t*>(kp + (size_t)(k0n + t * 16) * 32);
#pragma unroll
                for (int kc = 0; kc < 2; ++kc)
#pragma unroll
                    for (int dh = 0; dh < 2; ++dh)
                        vtN[kc][dh] = *reinterpret_cast<const bf8_t*>(vp + (size_t)(itn * 2 + kc) * 1024 + dh * 512);
            }
#pragma unroll
            for (int kh = 0; kh < 4; ++kh) {
                float e0 = fastexp(st[kh][0]);
                float e1 = fastexp(st[kh][1]);
                float e2 = fastexp(st[kh][2]);
                float e3 = fastexp(st[kh][3]);
                uint2 pk;
                pk.x = pack_trunc(e0, e1);
                pk.y = pack_trunc(e2, e3);
                *reinterpret_cast<uint2*>(plw + kh * 16) = pk;
            }
        }
#pragma unroll
        for (int qt = 1; qt < 4; ++qt) {
            f4_t st[4];
#pragma unroll
            for (int kh = 0; kh < 4; ++kh)
                st[kh] = __builtin_amdgcn_mfma_f32_16x16x32_bf16(kfC[kh], qf[qt], zf, 0, 0, 0);
#pragma unroll
            for (int kh = 0; kh < 4; ++kh) {
                float e0 = fastexp(st[kh][0]);
                float e1 = fastexp(st[kh][1]);
                float e2 = fastexp(st[kh][2]);
                float e3 = fastexp(st[kh][3]);
                uint2 pk;
                pk.x = pack_trunc(e0, e1);
                pk.y = pack_trunc(e2, e3);
                *reinterpret_cast<uint2*>(plw + qt * 1152 + kh * 16) = pk;
            }
        }
#pragma unroll
        for (int qt = 0; qt < 4; ++qt) {
#pragma unroll
            for (int kc = 0; kc < 2; ++kc) {
                bf8_t pf = *reinterpret_cast<const bf8_t*>(plr + qt * 1152 + kc * 32);
                o[0][qt] = __builtin_amdgcn_mfma_f32_16x16x32_bf16(vtC[kc][0], pf, o[0][qt], 0, 0, 0);
                o[1][qt] = __builtin_amdgcn_mfma_f32_16x16x32_bf16(vtC[kc][1], pf, o[1][qt], 0, 0, 0);
                lacc[qt] = __builtin_amdgcn_mfma_f32_16x16x32_bf16(ones, pf, lacc[qt], 0, 0, 0);
            }
        }
    };

    for (int it = 0; it < 16; it += 2) {
        step(kfA, vtA, kfB, vtB, it + 1);
        step(kfB, vtB, kfA, vtA, it + 2);
    }

#pragma unroll
    for (int qt = 0; qt < 4; ++qt) {
        float inv = 1.f / lacc[qt][0];
        size_t base = ((size_t)(u * S_ + q0 + qt * 16 + ln15)) * C_ + h * DH_;
#pragma unroll
        for (int dh = 0; dh < 2; ++dh) {
            ushort4 pk;
            pk.x = f2bu(o[dh][qt][0] * inv);
            pk.y = f2bu(o[dh][qt][1] * inv);
            pk.z = f2bu(o[dh][qt][2] * inv);
            pk.w = f2bu(o[dh][qt][3] * inv);
            *reinterpret_cast<ushort4*>(ctx + base + dh * 16 + quad * 4) = pk;
        }
    }
}

// ---- fused tail v5: weight-fragment register prefetch in all 3 GEMM phases ----
__global__ __launch_bounds__(512) void fused_tail(
    const bf16* __restrict__ ctx, const bf16* __restrict__ wout,
    const float* __restrict__ bout, const float* __restrict__ z,
    const int* __restrict__ pair, const float* __restrict__ gatef,
    const float* __restrict__ res_scale,
    const float* __restrict__ lnw, const float* __restrict__ lnb,
    const bf16* __restrict__ w1b, const float* __restrict__ b1,
    const bf16* __restrict__ w2b, const float* __restrict__ b2,
    float* __restrict__ outp) {
    __shared__ __align__(16) short Xs[32][264];
    __shared__ __align__(16) short CHs[32][264];  // ctx tile in phase A, then h tile
    __shared__ float ssum[8][32], ssq[8][32], smean[32], srstd[32];

    int tid = threadIdx.x;
    int wv = tid >> 6, lane = tid & 63;
    int ln15 = lane & 15, quad = lane >> 4;
    int u = blockIdx.x >> 5;
    int s0 = (blockIdx.x & 31) * 32;
    int bi = pair[u];
    float g = res_scale[0] * gatef[u >> 1];
    int c0 = wv * 32;

    // stage ctx tile [32 tok][256 c] coalesced
    {
        int row = tid >> 4, col = (tid & 15) * 16;
        const bf16* src = ctx + ((size_t)(u * S_ + s0 + row)) * 256 + col;
        *reinterpret_cast<bf8_t*>(&CHs[row][col]) = *reinterpret_cast<const bf8_t*>(src);
        *reinterpret_cast<bf8_t*>(&CHs[row][col + 8]) = *reinterpret_cast<const bf8_t*>(src + 8);
    }
    __syncthreads();

    // ---- phase A: y^T = Wout·ctx^T (+bias, +z, ×gate), wf prefetched ----
    f4_t yacc[2][2];
#pragma unroll
    for (int i = 0; i < 2; ++i)
#pragma unroll
        for (int j = 0; j < 2; ++j) yacc[i][j] = (f4_t)(0.0f);
    {
        const bf16* Wb = wout + (((size_t)(wv * 2) * 8) << 9) + lane * 8;
        bf8_t wA[2], wB[2];
#pragma unroll
        for (int i = 0; i < 2; ++i)
            wA[i] = *reinterpret_cast<const bf8_t*>(Wb + ((size_t)(i * 8) << 9));
        auto stepA = [&](bf8_t (&cur)[2], bf8_t (&nxt)[2], int kch) {
            if (kch + 1 < 8)
#pragma unroll
                for (int i = 0; i < 2; ++i)
                    nxt[i] = *reinterpret_cast<const bf8_t*>(Wb + ((size_t)(i * 8 + kch + 1) << 9));
            bf8_t xf[2];
#pragma unroll
            for (int j = 0; j < 2; ++j)
                xf[j] = *reinterpret_cast<const bf8_t*>(&CHs[j * 16 + ln15][kch * 32 + quad * 8]);
#pragma unroll
            for (int i = 0; i < 2; ++i)
#pragma unroll
                for (int j = 0; j < 2; ++j)
                    yacc[i][j] = __builtin_amdgcn_mfma_f32_16x16x32_bf16(cur[i], xf[j], yacc[i][j], 0, 0, 0);
        };
        for (int kch = 0; kch < 8; kch += 2) {
            stepA(wA, wB, kch);
            stepA(wB, wA, kch + 1);
        }
    }
    // epilogue A: bias + gated residual; LN stats
    float psum[2] = {0.f, 0.f}, psq[2] = {0.f, 0.f};
#pragma unroll
    for (int i = 0; i < 2; ++i) {
#pragma unroll
        for (int r = 0; r < 4; ++r) {
            int c = c0 + i * 16 + quad * 4 + r;
            float bs = bout[c];
            const float* zr = z + ((size_t)bi * C_ + c) * S_ + s0;
#pragma unroll
            for (int j = 0; j < 2; ++j) {
                int sl = j * 16 + ln15;
                float y = zr[sl] + g * (yacc[i][j][r] + bs);
                yacc[i][j][r] = y;
                psum[j] += y;
                psq[j] += y * y;
            }
        }
    }
#pragma unroll
    for (int j = 0; j < 2; ++j) {
        psum[j] += __shfl_xor(psum[j], 16);
        psum[j] += __shfl_xor(psum[j], 32);
        psq[j] += __shfl_xor(psq[j], 16);
        psq[j] += __shfl_xor(psq[j], 32);
    }
    if (quad == 0) {
#pragma unroll
        for (int j = 0; j < 2; ++j) {
            ssum[wv][j * 16 + ln15] = psum[j];
            ssq[wv][j * 16 + ln15] = psq[j];
        }
    }
    __syncthreads();
    if (tid < 32) {
        float sm = 0.f, q2 = 0.f;
#pragma unroll
        for (int w = 0; w < 8; ++w) {
            sm += ssum[w][tid];
            q2 += ssq[w][tid];
        }
        float mean = sm * (1.0f / C_);
        float var = q2 * (1.0f / C_) - mean * mean;
        smean[tid] = mean;
        srstd[tid] = rsqrtf(var + 1e-5f);
    }
    __syncthreads();
    // write x_ln to Xs
#pragma unroll
    for (int j = 0; j < 2; ++j) {
        int sl = j * 16 + ln15;
        float mean = smean[sl], rstd = srstd[sl];
#pragma unroll
        for (int i = 0; i < 2; ++i) {
            ushort4 pk;
#pragma unroll
            for (int r = 0; r < 4; ++r) {
                int c = c0 + i * 16 + quad * 4 + r;
                float xv = (yacc[i][j][r] - mean) * rstd * lnw[c] + lnb[c];
                ((unsigned short*)&pk)[r] = f2bu(xv);
            }
            *reinterpret_cast<ushort4*>(&Xs[sl][c0 + i * 16 + quad * 4]) = pk;
        }
    }
    __syncthreads();

    // ---- 4 passes: fc1+GELU then fc2 accumulation, wf prefetched ----
    f4_t acc2[2][2];
#pragma unroll
    for (int i = 0; i < 2; ++i)
#pragma unroll
        for (int j = 0; j < 2; ++j) acc2[i][j] = (f4_t)(0.0f);

    for (int pass = 0; pass < 4; ++pass) {
        f4_t hacc[2][2];
#pragma unroll
        for (int i = 0; i < 2; ++i)
#pragma unroll
            for (int j = 0; j < 2; ++j) hacc[i][j] = (f4_t)(0.0f);
        {
            const bf16* W1p = w1b + (((size_t)(pass * 16 + wv * 2) * 8) << 9) + lane * 8;
            bf8_t wA[2], wB[2];
#pragma unroll
            for (int i = 0; i < 2; ++i)
                wA[i] = *reinterpret_cast<const bf8_t*>(W1p + ((size_t)(i * 8) << 9));
            auto step1 = [&](bf8_t (&cur)[2], bf8_t (&nxt)[2], int kch) {
                if (kch + 1 < 8)
#pragma unroll
                    for (int i = 0; i < 2; ++i)
                        nxt[i] = *reinterpret_cast<const bf8_t*>(W1p + ((size_t)(i * 8 + kch + 1) << 9));
                bf8_t xf[2];
#pragma unroll
                for (int j = 0; j < 2; ++j)
                    xf[j] = *reinterpret_cast<const bf8_t*>(&Xs[j * 16 + ln15][kch * 32 + quad * 8]);
#pragma unroll
                for (int i = 0; i < 2; ++i)
#pragma unroll
                    for (int j = 0; j < 2; ++j)
                        hacc[i][j] = __builtin_amdgcn_mfma_f32_16x16x32_bf16(cur[i], xf[j], hacc[i][j], 0, 0, 0);
            };
            for (int kch = 0; kch < 8; kch += 2) {
                step1(wA, wB, kch);
                step1(wB, wA, kch + 1);
            }
        }
        // GELU -> CHs (h tile)
#pragma unroll
        for (int j = 0; j < 2; ++j) {
#pragma unroll
            for (int i = 0; i < 2; ++i) {
                ushort4 pk;
#pragma unroll
                for (int r = 0; r < 4; ++r) {
                    int hg = pass * 256 + c0 + i * 16 + quad * 4 + r;
                    float v = hacc[i][j][r] + b1[hg];
                    float ge = 0.5f * v * (1.f + erff(v * 0.70710678118f));
                    ((unsigned short*)&pk)[r] = f2bu(ge);
                }
                *reinterpret_cast<ushort4*>(&CHs[j * 16 + ln15][c0 + i * 16 + quad * 4]) = pk;
            }
        }
        __syncthreads();
        // fc2 accumulation over this h-slice
        {
            const bf16* W2p = w2b + (((size_t)(wv * 2) * 32 + pass * 8) << 9) + lane * 8;
            bf8_t wA[2], wB[2];
#pragma unroll
            for (int i = 0; i < 2; ++i)
                wA[i] = *reinterpret_cast<const bf8_t*>(W2p + ((size_t)(i * 32) << 9));
            auto step2 = [&](bf8_t (&cur)[2], bf8_t (&nxt)[2], int kch) {
                if (kch + 1 < 8)
#pragma unroll
                    for (int i = 0; i < 2; ++i)
                        nxt[i] = *reinterpret_cast<const bf8_t*>(W2p + ((size_t)(i * 32 + kch + 1) << 9));
                bf8_t hf[2];
#pragma unroll
                for (int j = 0; j < 2; ++j)
                    hf[j] = *reinterpret_cast<const bf8_t*>(&CHs[j * 16 + ln15][kch * 32 + quad * 8]);
#pragma unroll
                for (int i = 0; i < 2; ++i)
#pragma unroll
                    for (int j = 0; j < 2; ++j)
                        acc2[i][j] = __builtin_amdgcn_mfma_f32_16x16x32_bf16(cur[i], hf[j], acc2[i][j], 0, 0, 0);
            };
            for (int kch = 0; kch < 8; kch += 2) {
                step2(wA, wB, kch);
                step2(wB, wA, kch + 1);
            }
        }
        __syncthreads();
    }

    // ---- final: out = y + mlp + b2, coalesced fp32 store ----
#pragma unroll
    for (int i = 0; i < 2; ++i) {
#pragma unroll
        for (int r = 0; r < 4; ++r) {
            int c = c0 + i * 16 + quad * 4 + r;
            float bs = b2[c];
            float* orow = outp + ((size_t)bi * C_ + c) * S_ + s0;
#pragma unroll
            for (int j = 0; j < 2; ++j)
                orow[j * 16 + ln15] = yacc[i][j][r] + acc2[i][j][r] + bs;
        }
    }
}

extern "C" void kernel_launch(void* const* d_in, const int* in_sizes, int n_in,
                              void* d_out, int out_size, void* d_ws, size_t ws_size,
                              hipStream_t stream) {
    const float* z = (const float*)d_in[0];
    const int* pair = (const int*)d_in[1];
    const float* ln_w = (const float*)d_in[2];
    const float* ln_b = (const float*)d_in[3];
    const float* in_proj_w = (const float*)d_in[4];
    const float* in_proj_b = (const float*)d_in[5];
    const float* out_proj_w = (const float*)d_in[6];
    const float* out_proj_b = (const float*)d_in[7];
    const float* res_scale = (const float*)d_in[8];
    const float* gate_scale = (const float*)d_in[9];
    const float* mlp_ln_w = (const float*)d_in[10];
    const float* mlp_ln_b = (const float*)d_in[11];
    const float* mlp_w1 = (const float*)d_in[12];
    const float* mlp_b1 = (const float*)d_in[13];
    const float* mlp_w2 = (const float*)d_in[14];
    const float* mlp_b2 = (const float*)d_in[15];
    float* out = (float*)d_out;

    char* ws = (char*)d_ws;
    bf16* qln = (bf16*)(ws);                        //  8 MB (A-fragment packed)
    bf16* qpk = (bf16*)(ws + 8388608);              //  8 MB
    bf16* kpk = (bf16*)(ws + 16777216);             //  8 MB
    bf16* vpk = (bf16*)(ws + 25165824);             //  8 MB
    bf16* ctx = (bf16*)(ws + 33554432);             //  8 MB
    bf16* wqkv = (bf16*)(ws + 41943040);            //  384 KB (packed)
    bf16* wout = (bf16*)(ws + 41943040 + 393216);   //  128 KB (packed)
    bf16* w1b = (bf16*)(ws + 41943040 + 524288);    //  512 KB (packed)
    bf16* w2b = (bf16*)(ws + 41943040 + 1048576);   //  512 KB (packed)
    float* partial = (float*)(ws + 50331648);       //  256 KB ([u][sb][c])
    float* gatef = (float*)(ws + 50331648 + 262144);

    // 1. LN (+partials) and weight packing in one launch
    prep_kernel<<<3328, 256, 0, stream>>>(z, pair, ln_w, ln_b, qln, partial,
                                          in_proj_w, wqkv, out_proj_w, wout,
                                          mlp_w1, w1b, mlp_w2, w2b);
    // 2. QKV projection (+ gate as block 768)
    gemm_qkv<<<769, 256, 0, stream>>>(qln, wqkv, in_proj_b, qpk, kpk, vpk,
                                      partial, gate_scale, gatef,
                                      out + 4194304, out + 4194312);
    // 3. cross attention (64 q/wave, 256 q/block, L1-shared K/V, XCD-swizzled)
    attn_mfma<<<512, 256, 0, stream>>>(qpk, kpk, vpk, ctx);
    // 4. fused tail: out-proj + residual + LN + MLP + residual -> d_out
    fused_tail<<<512, 512, 0, stream>>>(ctx, wout, out_proj_b, z, pair, gatef, res_scale,
                                        mlp_ln_w, mlp_ln_b, w1b, mlp_b1, w2b, mlp_b2, out);
}

// Round 17
// 203.664 us; speedup vs baseline: 1.0293x; 1.0293x over previous
//
#include <hip/hip_runtime.h>
#include <hip/hip_bf16.h>

#define C_ 256
#define S_ 1024
#define NH_ 8
#define DH_ 32
#define NSIDE 16
#define MTOT (NSIDE * S_) // 16384

typedef __hip_bfloat16 bf16;
typedef short bf8_t __attribute__((ext_vector_type(8)));  // 8 bf16 = 4 VGPRs
typedef float f4_t __attribute__((ext_vector_type(4)));   // 4 fp32 acc

// exp path: prefer raw v_exp_f32 (exp2) with log2e folded into the Q scale
#if __has_builtin(__builtin_amdgcn_exp2f)
#define QSCALE 0.25504167f  // 1/sqrt(32) * log2(e)
__device__ __forceinline__ float fastexp(float x) { return __builtin_amdgcn_exp2f(x); }
#else
#define QSCALE 0.17677669529663689f  // 1/sqrt(32)
__device__ __forceinline__ float fastexp(float x) { return __expf(x); }
#endif

__device__ __forceinline__ float b2f(bf16 x) { return __bfloat162float(x); }
__device__ __forceinline__ bf16 f2b(float x) { return __float2bfloat16(x); }
__device__ __forceinline__ unsigned short f2bu(float x) {
    bf16 h = f2b(x);
    return *reinterpret_cast<unsigned short*>(&h);
}
// truncating pack of two floats to bf16x2 via one v_perm_b32
__device__ __forceinline__ unsigned pack_trunc(float a, float b) {
    return __builtin_amdgcn_perm(__float_as_uint(b), __float_as_uint(a), 0x07060302u);
}

__device__ __forceinline__ float block_sum(float v, float* red) {
#pragma unroll
    for (int off = 1; off < 64; off <<= 1) v += __shfl_xor(v, off);
    __syncthreads();
    if ((threadIdx.x & 63) == 0) red[threadIdx.x >> 6] = v;
    __syncthreads();
    float r = red[0] + red[1] + red[2] + red[3];
    __syncthreads();
    return r;
}

// Fragment-major packing: element (n,k) of an [N][K] matrix ->
// block (n>>4, k>>5) of 512 elems; within block: [(k>>3)&3][n&15][k&7]
__device__ __forceinline__ void packone(const float* __restrict__ src, bf16* __restrict__ dst,
                                        int i, int kshift) {
    int n = i >> kshift, k = i & ((1 << kshift) - 1);
    size_t a = ((size_t)((n >> 4) * (1 << (kshift - 5)) + (k >> 5)) << 9) +
               (((k >> 3) & 3) << 7) + ((n & 15) << 3) + (k & 7);
    dst[a] = f2b(src[i]);
}

// ---- prep: blocks 0..255 = LN of pair tokens (+ mean partials); 256+ = weight packing ----
__global__ __launch_bounds__(256) void prep_kernel(
    const float* __restrict__ src, const int* __restrict__ pair,
    const float* __restrict__ w, const float* __restrict__ b,
    bf16* __restrict__ dst, float* __restrict__ partial,
    const float* __restrict__ wa, bf16* __restrict__ oa,
    const float* __restrict__ wb_, bf16* __restrict__ ob,
    const float* __restrict__ wc, bf16* __restrict__ oc,
    const float* __restrict__ wd, bf16* __restrict__ od) {
    int bid = blockIdx.x;
    if (bid >= 256) {
        int i = (bid - 256) * 256 + threadIdx.x;
        if (i < 196608) { packone(wa, oa, i, 8); return; }       // in_proj_w 768x256
        i -= 196608;
        if (i < 65536) { packone(wb_, ob, i, 8); return; }       // out_proj_w 256x256
        i -= 65536;
        if (i < 262144) { packone(wc, oc, i, 8); return; }       // mlp_w1 1024x256
        i -= 262144;
        if (i < 262144) packone(wd, od, i, 10);                  // mlp_w2 256x1024
        return;
    }
    __shared__ float psum[4][64], psq[4][64], mean_s[64], rstd_s[64];
    __shared__ float wb[512];
    __shared__ __align__(16) short Ys[64][264];
    int sb = bid & 15, u = bid >> 4;
    int bi = pair[u];
    int tid = threadIdx.x;
    wb[tid] = w[tid];
    wb[256 + tid] = b[tid];
    int sl = tid & 63, cp = tid >> 6;
    int s = sb * 64 + sl;
    const float* zb = src + (size_t)bi * C_ * S_ + s;
    float sum = 0.f, sq = 0.f;
    for (int c = cp * 64; c < cp * 64 + 64; ++c) {
        float x = zb[(size_t)c * S_];
        sum += x;
        sq += x * x;
    }
    psum[cp][sl] = sum;
    psq[cp][sl] = sq;
    __syncthreads();
    if (tid < 64) {
        float sm = psum[0][tid] + psum[1][tid] + psum[2][tid] + psum[3][tid];
        float q2 = psq[0][tid] + psq[1][tid] + psq[2][tid] + psq[3][tid];
        float mean = sm * (1.0f / C_);
        float var = q2 * (1.0f / C_) - mean * mean;
        mean_s[tid] = mean;
        rstd_s[tid] = rsqrtf(var + 1e-5f);
    }
    __syncthreads();
    float mean = mean_s[sl], rstd = rstd_s[sl];
    int m = u * S_ + s;
    size_t tile8 = (size_t)(m >> 4) * 8;
    for (int c8 = 0; c8 < 64; c8 += 8) {
        int c = cp * 64 + c8;
        bf8_t pk;
#pragma unroll
        for (int j = 0; j < 8; ++j) {
            float x = zb[(size_t)(c + j) * S_];
            float y = (x - mean) * rstd * wb[c + j] + wb[256 + c + j];
            pk[j] = (short)f2bu(y);
        }
        *reinterpret_cast<bf8_t*>(&Ys[sl][c]) = pk;
        *reinterpret_cast<bf8_t*>(dst + ((tile8 + (c >> 5)) << 9) +
                                  (((c >> 3) & 3) << 7) + ((m & 15) << 3)) = pk;
    }
    __syncthreads();
    float csum = 0.f;
#pragma unroll 8
    for (int t = 0; t < 64; ++t)
        csum += b2f(*reinterpret_cast<const bf16*>(&Ys[t][tid]));
    partial[((size_t)u * 16 + sb) * C_ + tid] = csum;
}

// ---- QKV projection GEMM (blocks 0..767) + gate (block 768) ----
// qpk/kpk: [u][h][tok][d]   vpk: [u][h][kt][d][key32]
__global__ __launch_bounds__(256) void gemm_qkv(
    const bf16* __restrict__ Apk, const bf16* __restrict__ Wpk, const float* __restrict__ bias,
    bf16* __restrict__ qpk, bf16* __restrict__ kpk, bf16* __restrict__ vpk,
    const float* __restrict__ partial, const float* __restrict__ gate_scale,
    float* __restrict__ gatef, float* __restrict__ out_gate, float* __restrict__ out_sim) {
    __shared__ float red[4];
    int tid = threadIdx.x;
    if (blockIdx.x == 768) {
        int c = tid;
        for (int p = 0; p < 8; ++p) {
            float mi = 0.f, mj = 0.f;
            for (int sy = 0; sy < 16; ++sy) {
                mi += partial[((size_t)(2 * p) * 16 + sy) * C_ + c];
                mj += partial[((size_t)(2 * p + 1) * 16 + sy) * C_ + c];
            }
            mi *= (1.f / S_);
            mj *= (1.f / S_);
            float ii = block_sum(mi * mi, red);
            float jj = block_sum(mj * mj, red);
            float ij = block_sum(mi * mj, red);
            if (c == 0) {
                float ni = fmaxf(sqrtf(ii), 1e-6f);
                float nj = fmaxf(sqrtf(jj), 1e-6f);
                float sim = ij / (ni * nj);
                float gate = 1.f / (1.f + expf(-gate_scale[0] * sim));
                gatef[p] = gate;
                out_gate[p] = gate;
                out_sim[p] = sim;
            }
        }
        return;
    }
    int wv = tid >> 6, lane = tid & 63;
    int ln15 = lane & 15, quad = lane >> 4;
    int idx = blockIdx.x * 4 + wv;
    int mt = idx / 12, nt = idx % 12;
    int m0 = mt * 64, n0 = nt * 64;

    f4_t acc[4][4];
#pragma unroll
    for (int i = 0; i < 4; ++i)
#pragma unroll
        for (int j = 0; j < 4; ++j) acc[i][j] = (f4_t)(0.0f);

    const bf16* Ab = Apk + ((size_t)mt << 14) + lane * 8;
    const bf16* Wb = Wpk + ((size_t)nt << 14) + lane * 8;

    bf8_t a0[4], w0[4], a1[4], w1[4];
#pragma unroll
    for (int i = 0; i < 4; ++i) {
        a0[i] = *reinterpret_cast<const bf8_t*>(Ab + ((size_t)(i * 8) << 9));
        w0[i] = *reinterpret_cast<const bf8_t*>(Wb + ((size_t)(i * 8) << 9));
    }
    for (int kch = 0; kch < 8; kch += 2) {
#pragma unroll
        for (int i = 0; i < 4; ++i) {
            a1[i] = *reinterpret_cast<const bf8_t*>(Ab + ((size_t)(i * 8 + kch + 1) << 9));
            w1[i] = *reinterpret_cast<const bf8_t*>(Wb + ((size_t)(i * 8 + kch + 1) << 9));
        }
#pragma unroll
        for (int i = 0; i < 4; ++i)
#pragma unroll
            for (int j = 0; j < 4; ++j)
                acc[i][j] = __builtin_amdgcn_mfma_f32_16x16x32_bf16(a0[i], w0[j], acc[i][j], 0, 0, 0);
        if (kch + 2 < 8) {
#pragma unroll
            for (int i = 0; i < 4; ++i) {
                a0[i] = *reinterpret_cast<const bf8_t*>(Ab + ((size_t)(i * 8 + kch + 2) << 9));
                w0[i] = *reinterpret_cast<const bf8_t*>(Wb + ((size_t)(i * 8 + kch + 2) << 9));
            }
        }
#pragma unroll
        for (int i = 0; i < 4; ++i)
#pragma unroll
            for (int j = 0; j < 4; ++j)
                acc[i][j] = __builtin_amdgcn_mfma_f32_16x16x32_bf16(a1[i], w1[j], acc[i][j], 0, 0, 0);
    }

#pragma unroll
    for (int i = 0; i < 4; ++i) {
#pragma unroll
        for (int j = 0; j < 4; ++j) {
            int coln = n0 + j * 16 + ln15;
            float bs = bias[coln];
            int row0 = m0 + i * 16 + quad * 4;   // r=0 row; u and kt uniform over r
            int u = row0 >> 10, s0v = row0 & 1023;
            if (coln < 256) {
                int h = coln >> 5, d = coln & 31;
                bf16* qp = qpk + (((size_t)u * 8 + h) * 1024 + s0v) * 32 + d;
#pragma unroll
                for (int r = 0; r < 4; ++r)
                    qp[r * 32] = f2b((acc[i][j][r] + bs) * QSCALE);
            } else if (coln < 512) {
                int c = coln - 256, h = c >> 5, d = c & 31;
                bf16* kp = kpk + (((size_t)u * 8 + h) * 1024 + s0v) * 32 + d;
#pragma unroll
                for (int r = 0; r < 4; ++r)
                    kp[r * 32] = f2b(acc[i][j][r] + bs);
            } else {
                int c = coln - 512, h = c >> 5, d = c & 31;
                ushort4 pk;  // 4 consecutive keys (r maps to s) -> one 8B store
#pragma unroll
                for (int r = 0; r < 4; ++r)
                    ((unsigned short*)&pk)[r] = f2bu(acc[i][j][r] + bs);
                *reinterpret_cast<ushort4*>(
                    vpk + ((((size_t)u * 8 + h) * 32 + (s0v >> 5)) * 32 + d) * 32 + (s0v & 31)) = pk;
            }
        }
    }
}

// ---- attention v8: 64 q/wave (4 qt), block = 256 q of one (u,h); waves share K/V in L1 ----
__global__ __launch_bounds__(256, 2) void attn_mfma(const bf16* __restrict__ qpk,
                                                    const bf16* __restrict__ kpk,
                                                    const bf16* __restrict__ vpk,
                                                    bf16* __restrict__ ctx) {
    __shared__ __align__(16) short smem[4 * 4608]; // per wave: 4 qt x 16 q x 72
    int tid = threadIdx.x;
    int wv = tid >> 6, lane = tid & 63;
    int ln15 = lane & 15, quad = lane >> 4;
    int bid = blockIdx.x;
    int g = bid >> 5, rem = bid & 31;
    int qb = rem >> 3, xcd = rem & 7;
    int uh = g * 8 + xcd;
    int u = uh >> 3, h = uh & 7, up = u ^ 1;
    int q0 = qb * 256 + wv * 64;
    short* PL = smem + wv * 4608;

    const bf16* Qb = qpk + (size_t)uh * 32768;
    const bf16* Kb = kpk + ((size_t)(up * 8 + h)) * 32768;
    const bf16* Vb = vpk + ((size_t)(up * 8 + h)) * 32768;

    bf8_t qf[4];
#pragma unroll
    for (int qt = 0; qt < 4; ++qt)
        qf[qt] = *reinterpret_cast<const bf8_t*>(Qb + (size_t)(q0 + qt * 16 + ln15) * 32 + quad * 8);

    bf8_t ones;
#pragma unroll
    for (int t = 0; t < 8; ++t) ones[t] = (short)0x3F80;

    const bf16* kp = Kb + ln15 * 32 + quad * 8;
    const bf16* vp = Vb + ln15 * 32 + quad * 8;
    short* plw = PL + ln15 * 72 + quad * 4;
    const short* plr = PL + ln15 * 72 + quad * 8;

    f4_t o[2][4];  // [dh][qt]
#pragma unroll
    for (int i = 0; i < 2; ++i)
#pragma unroll
        for (int j = 0; j < 4; ++j) o[i][j] = (f4_t)(0.0f);
    f4_t lacc[4];
#pragma unroll
    for (int j = 0; j < 4; ++j) lacc[j] = (f4_t)(0.0f);
    f4_t zf = (f4_t)(0.0f);

    bf8_t kfA[4], vtA[2][2], kfB[4], vtB[2][2];
#pragma unroll
    for (int t = 0; t < 4; ++t)
        kfA[t] = *reinterpret_cast<const bf8_t*>(kp + (size_t)(t * 16) * 32);
#pragma unroll
    for (int kc = 0; kc < 2; ++kc)
#pragma unroll
        for (int dh = 0; dh < 2; ++dh)
            vtA[kc][dh] = *reinterpret_cast<const bf8_t*>(vp + (size_t)kc * 1024 + dh * 512);

    auto step = [&](bf8_t (&kfC)[4], bf8_t (&vtC)[2][2],
                    bf8_t (&kfN)[4], bf8_t (&vtN)[2][2], int itn) {
        {
            f4_t st[4];
#pragma unroll
            for (int kh = 0; kh < 4; ++kh)
                st[kh] = __builtin_amdgcn_mfma_f32_16x16x32_bf16(kfC[kh], qf[0], zf, 0, 0, 0);
            if (itn < 16) {
                int k0n = itn * 64;
#pragma unroll
                for (int t = 0; t < 4; ++t)
                    kfN[t] = *reinterpret_cast<const bf8_t*>(kp + (size_t)(k0n + t * 16) * 32);
#pragma unroll
                for (int kc = 0; kc < 2; ++kc)
#pragma unroll
                    for (int dh = 0; dh < 2; ++dh)
                        vtN[kc][dh] = *reinterpret_cast<const bf8_t*>(vp + (size_t)(itn * 2 + kc) * 1024 + dh * 512);
            }
#pragma unroll
            for (int kh = 0; kh < 4; ++kh) {
                float e0 = fastexp(st[kh][0]);
                float e1 = fastexp(st[kh][1]);
                float e2 = fastexp(st[kh][2]);
                float e3 = fastexp(st[kh][3]);
                uint2 pk;
                pk.x = pack_trunc(e0, e1);
                pk.y = pack_trunc(e2, e3);
                *reinterpret_cast<uint2*>(plw + kh * 16) = pk;
            }
        }
#pragma unroll
        for (int qt = 1; qt < 4; ++qt) {
            f4_t st[4];
#pragma unroll
            for (int kh = 0; kh < 4; ++kh)
                st[kh] = __builtin_amdgcn_mfma_f32_16x16x32_bf16(kfC[kh], qf[qt], zf, 0, 0, 0);
#pragma unroll
            for (int kh = 0; kh < 4; ++kh) {
                float e0 = fastexp(st[kh][0]);
                float e1 = fastexp(st[kh][1]);
                float e2 = fastexp(st[kh][2]);
                float e3 = fastexp(st[kh][3]);
                uint2 pk;
                pk.x = pack_trunc(e0, e1);
                pk.y = pack_trunc(e2, e3);
                *reinterpret_cast<uint2*>(plw + qt * 1152 + kh * 16) = pk;
            }
        }
#pragma unroll
        for (int qt = 0; qt < 4; ++qt) {
#pragma unroll
            for (int kc = 0; kc < 2; ++kc) {
                bf8_t pf = *reinterpret_cast<const bf8_t*>(plr + qt * 1152 + kc * 32);
                o[0][qt] = __builtin_amdgcn_mfma_f32_16x16x32_bf16(vtC[kc][0], pf, o[0][qt], 0, 0, 0);
                o[1][qt] = __builtin_amdgcn_mfma_f32_16x16x32_bf16(vtC[kc][1], pf, o[1][qt], 0, 0, 0);
                lacc[qt] = __builtin_amdgcn_mfma_f32_16x16x32_bf16(ones, pf, lacc[qt], 0, 0, 0);
            }
        }
    };

    for (int it = 0; it < 16; it += 2) {
        step(kfA, vtA, kfB, vtB, it + 1);
        step(kfB, vtB, kfA, vtA, it + 2);
    }

#pragma unroll
    for (int qt = 0; qt < 4; ++qt) {
        float inv = 1.f / lacc[qt][0];
        size_t base = ((size_t)(u * S_ + q0 + qt * 16 + ln15)) * C_ + h * DH_;
#pragma unroll
        for (int dh = 0; dh < 2; ++dh) {
            ushort4 pk;
            pk.x = f2bu(o[dh][qt][0] * inv);
            pk.y = f2bu(o[dh][qt][1] * inv);
            pk.z = f2bu(o[dh][qt][2] * inv);
            pk.w = f2bu(o[dh][qt][3] * inv);
            *reinterpret_cast<ushort4*>(ctx + base + dh * 16 + quad * 4) = pk;
        }
    }
}

// ---- fused tail v4: packed weight loads (1KB contiguous per fragment) ----
__global__ __launch_bounds__(512) void fused_tail(
    const bf16* __restrict__ ctx, const bf16* __restrict__ wout,
    const float* __restrict__ bout, const float* __restrict__ z,
    const int* __restrict__ pair, const float* __restrict__ gatef,
    const float* __restrict__ res_scale,
    const float* __restrict__ lnw, const float* __restrict__ lnb,
    const bf16* __restrict__ w1b, const float* __restrict__ b1,
    const bf16* __restrict__ w2b, const float* __restrict__ b2,
    float* __restrict__ outp) {
    __shared__ __align__(16) short Xs[32][264];
    __shared__ __align__(16) short CHs[32][264];  // ctx tile in phase A, then h tile
    __shared__ float ssum[8][32], ssq[8][32], smean[32], srstd[32];

    int tid = threadIdx.x;
    int wv = tid >> 6, lane = tid & 63;
    int ln15 = lane & 15, quad = lane >> 4;
    int u = blockIdx.x >> 5;
    int s0 = (blockIdx.x & 31) * 32;
    int bi = pair[u];
    float g = res_scale[0] * gatef[u >> 1];
    int c0 = wv * 32;

    // stage ctx tile [32 tok][256 c] coalesced
    {
        int row = tid >> 4, col = (tid & 15) * 16;
        const bf16* src = ctx + ((size_t)(u * S_ + s0 + row)) * 256 + col;
        *reinterpret_cast<bf8_t*>(&CHs[row][col]) = *reinterpret_cast<const bf8_t*>(src);
        *reinterpret_cast<bf8_t*>(&CHs[row][col + 8]) = *reinterpret_cast<const bf8_t*>(src + 8);
    }
    __syncthreads();

    // ---- phase A: y^T = Wout·ctx^T (+bias, +z, ×gate) ----
    f4_t yacc[2][2];
#pragma unroll
    for (int i = 0; i < 2; ++i)
#pragma unroll
        for (int j = 0; j < 2; ++j) yacc[i][j] = (f4_t)(0.0f);
    {
        const bf16* Wb = wout + (((size_t)(wv * 2) * 8) << 9) + lane * 8;
#pragma unroll
        for (int kch = 0; kch < 8; ++kch) {
            bf8_t wf[2], xf[2];
#pragma unroll
            for (int i = 0; i < 2; ++i)
                wf[i] = *reinterpret_cast<const bf8_t*>(Wb + ((size_t)(i * 8 + kch) << 9));
#pragma unroll
            for (int j = 0; j < 2; ++j)
                xf[j] = *reinterpret_cast<const bf8_t*>(&CHs[j * 16 + ln15][kch * 32 + quad * 8]);
#pragma unroll
            for (int i = 0; i < 2; ++i)
#pragma unroll
                for (int j = 0; j < 2; ++j)
                    yacc[i][j] = __builtin_amdgcn_mfma_f32_16x16x32_bf16(wf[i], xf[j], yacc[i][j], 0, 0, 0);
        }
    }
    // epilogue A: bias + gated residual; LN stats
    float psum[2] = {0.f, 0.f}, psq[2] = {0.f, 0.f};
#pragma unroll
    for (int i = 0; i < 2; ++i) {
#pragma unroll
        for (int r = 0; r < 4; ++r) {
            int c = c0 + i * 16 + quad * 4 + r;
            float bs = bout[c];
            const float* zr = z + ((size_t)bi * C_ + c) * S_ + s0;
#pragma unroll
            for (int j = 0; j < 2; ++j) {
                int sl = j * 16 + ln15;
                float y = zr[sl] + g * (yacc[i][j][r] + bs);
                yacc[i][j][r] = y;
                psum[j] += y;
                psq[j] += y * y;
            }
        }
    }
#pragma unroll
    for (int j = 0; j < 2; ++j) {
        psum[j] += __shfl_xor(psum[j], 16);
        psum[j] += __shfl_xor(psum[j], 32);
        psq[j] += __shfl_xor(psq[j], 16);
        psq[j] += __shfl_xor(psq[j], 32);
    }
    if (quad == 0) {
#pragma unroll
        for (int j = 0; j < 2; ++j) {
            ssum[wv][j * 16 + ln15] = psum[j];
            ssq[wv][j * 16 + ln15] = psq[j];
        }
    }
    __syncthreads();
    if (tid < 32) {
        float sm = 0.f, q2 = 0.f;
#pragma unroll
        for (int w = 0; w < 8; ++w) {
            sm += ssum[w][tid];
            q2 += ssq[w][tid];
        }
        float mean = sm * (1.0f / C_);
        float var = q2 * (1.0f / C_) - mean * mean;
        smean[tid] = mean;
        srstd[tid] = rsqrtf(var + 1e-5f);
    }
    __syncthreads();
    // write x_ln to Xs
#pragma unroll
    for (int j = 0; j < 2; ++j) {
        int sl = j * 16 + ln15;
        float mean = smean[sl], rstd = srstd[sl];
#pragma unroll
        for (int i = 0; i < 2; ++i) {
            ushort4 pk;
#pragma unroll
            for (int r = 0; r < 4; ++r) {
                int c = c0 + i * 16 + quad * 4 + r;
                float xv = (yacc[i][j][r] - mean) * rstd * lnw[c] + lnb[c];
                ((unsigned short*)&pk)[r] = f2bu(xv);
            }
            *reinterpret_cast<ushort4*>(&Xs[sl][c0 + i * 16 + quad * 4]) = pk;
        }
    }
    __syncthreads();

    // ---- 4 passes: fc1+GELU then fc2 accumulation ----
    f4_t acc2[2][2];
#pragma unroll
    for (int i = 0; i < 2; ++i)
#pragma unroll
        for (int j = 0; j < 2; ++j) acc2[i][j] = (f4_t)(0.0f);

    for (int pass = 0; pass < 4; ++pass) {
        f4_t hacc[2][2];
#pragma unroll
        for (int i = 0; i < 2; ++i)
#pragma unroll
            for (int j = 0; j < 2; ++j) hacc[i][j] = (f4_t)(0.0f);
        {
            const bf16* W1p = w1b + (((size_t)(pass * 16 + wv * 2) * 8) << 9) + lane * 8;
#pragma unroll
            for (int kch = 0; kch < 8; ++kch) {
                bf8_t wf[2], xf[2];
#pragma unroll
                for (int i = 0; i < 2; ++i)
                    wf[i] = *reinterpret_cast<const bf8_t*>(W1p + ((size_t)(i * 8 + kch) << 9));
#pragma unroll
                for (int j = 0; j < 2; ++j)
                    xf[j] = *reinterpret_cast<const bf8_t*>(&Xs[j * 16 + ln15][kch * 32 + quad * 8]);
#pragma unroll
                for (int i = 0; i < 2; ++i)
#pragma unroll
                    for (int j = 0; j < 2; ++j)
                        hacc[i][j] = __builtin_amdgcn_mfma_f32_16x16x32_bf16(wf[i], xf[j], hacc[i][j], 0, 0, 0);
            }
        }
        // GELU -> CHs (h tile)
#pragma unroll
        for (int j = 0; j < 2; ++j) {
#pragma unroll
            for (int i = 0; i < 2; ++i) {
                ushort4 pk;
#pragma unroll
                for (int r = 0; r < 4; ++r) {
                    int hg = pass * 256 + c0 + i * 16 + quad * 4 + r;
                    float v = hacc[i][j][r] + b1[hg];
                    float ge = 0.5f * v * (1.f + erff(v * 0.70710678118f));
                    ((unsigned short*)&pk)[r] = f2bu(ge);
                }
                *reinterpret_cast<ushort4*>(&CHs[j * 16 + ln15][c0 + i * 16 + quad * 4]) = pk;
            }
        }
        __syncthreads();
        // fc2 accumulation over this h-slice
        {
            const bf16* W2p = w2b + (((size_t)(wv * 2) * 32 + pass * 8) << 9) + lane * 8;
#pragma unroll
            for (int kch = 0; kch < 8; ++kch) {
                bf8_t wf[2], hf[2];
#pragma unroll
                for (int i = 0; i < 2; ++i)
                    wf[i] = *reinterpret_cast<const bf8_t*>(W2p + ((size_t)(i * 32 + kch) << 9));
#pragma unroll
                for (int j = 0; j < 2; ++j)
                    hf[j] = *reinterpret_cast<const bf8_t*>(&CHs[j * 16 + ln15][kch * 32 + quad * 8]);
#pragma unroll
                for (int i = 0; i < 2; ++i)
#pragma unroll
                    for (int j = 0; j < 2; ++j)
                        acc2[i][j] = __builtin_amdgcn_mfma_f32_16x16x32_bf16(wf[i], hf[j], acc2[i][j], 0, 0, 0);
            }
        }
        __syncthreads();
    }

    // ---- final: out = y + mlp + b2, coalesced fp32 store ----
#pragma unroll
    for (int i = 0; i < 2; ++i) {
#pragma unroll
        for (int r = 0; r < 4; ++r) {
            int c = c0 + i * 16 + quad * 4 + r;
            float bs = b2[c];
            float* orow = outp + ((size_t)bi * C_ + c) * S_ + s0;
#pragma unroll
            for (int j = 0; j < 2; ++j)
                orow[j * 16 + ln15] = yacc[i][j][r] + acc2[i][j][r] + bs;
        }
    }
}

extern "C" void kernel_launch(void* const* d_in, const int* in_sizes, int n_in,
                              void* d_out, int out_size, void* d_ws, size_t ws_size,
                              hipStream_t stream) {
    const float* z = (const float*)d_in[0];
    const int* pair = (const int*)d_in[1];
    const float* ln_w = (const float*)d_in[2];
    const float* ln_b = (const float*)d_in[3];
    const float* in_proj_w = (const float*)d_in[4];
    const float* in_proj_b = (const float*)d_in[5];
    const float* out_proj_w = (const float*)d_in[6];
    const float* out_proj_b = (const float*)d_in[7];
    const float* res_scale = (const float*)d_in[8];
    const float* gate_scale = (const float*)d_in[9];
    const float* mlp_ln_w = (const float*)d_in[10];
    const float* mlp_ln_b = (const float*)d_in[11];
    const float* mlp_w1 = (const float*)d_in[12];
    const float* mlp_b1 = (const float*)d_in[13];
    const float* mlp_w2 = (const float*)d_in[14];
    const float* mlp_b2 = (const float*)d_in[15];
    float* out = (float*)d_out;

    char* ws = (char*)d_ws;
    bf16* qln = (bf16*)(ws);                        //  8 MB (A-fragment packed)
    bf16* qpk = (bf16*)(ws + 8388608);              //  8 MB
    bf16* kpk = (bf16*)(ws + 16777216);             //  8 MB
    bf16* vpk = (bf16*)(ws + 25165824);             //  8 MB
    bf16* ctx = (bf16*)(ws + 33554432);             //  8 MB
    bf16* wqkv = (bf16*)(ws + 41943040);            //  384 KB (packed)
    bf16* wout = (bf16*)(ws + 41943040 + 393216);   //  128 KB (packed)
    bf16* w1b = (bf16*)(ws + 41943040 + 524288);    //  512 KB (packed)
    bf16* w2b = (bf16*)(ws + 41943040 + 1048576);   //  512 KB (packed)
    float* partial = (float*)(ws + 50331648);       //  256 KB ([u][sb][c])
    float* gatef = (float*)(ws + 50331648 + 262144);

    // 1. LN (+partials) and weight packing in one launch
    prep_kernel<<<3328, 256, 0, stream>>>(z, pair, ln_w, ln_b, qln, partial,
                                          in_proj_w, wqkv, out_proj_w, wout,
                                          mlp_w1, w1b, mlp_w2, w2b);
    // 2. QKV projection (+ gate as block 768)
    gemm_qkv<<<769, 256, 0, stream>>>(qln, wqkv, in_proj_b, qpk, kpk, vpk,
                                      partial, gate_scale, gatef,
                                      out + 4194304, out + 4194312);
    // 3. cross attention (64 q/wave, 256 q/block, L1-shared K/V, XCD-swizzled)
    attn_mfma<<<512, 256, 0, stream>>>(qpk, kpk, vpk, ctx);
    // 4. fused tail: out-proj + residual + LN + MLP + residual -> d_out
    fused_tail<<<512, 512, 0, stream>>>(ctx, wout, out_proj_b, z, pair, gatef, res_scale,
                                        mlp_ln_w, mlp_ln_b, w1b, mlp_b1, w2b, mlp_b2, out);
}